// Round 3
// baseline (270.309 us; speedup 1.0000x reference)
//
#include <hip/hip_runtime.h>
#include <math.h>

#define B 64
#define SDIM 2048
#define FEAT 128
#define P 4
#define PK 8196
#define NCLS 7
#define PER 1000
#define NDATA 100000
#define EPSC 1e-7f
#define M_PN 0.08192f   /* (PK-P)/NDATA = 8192/100000 */
#define JCHUNKS 50
#define CS (PER / JCHUNKS)   /* 20 rows per block */
#define DCHUNK 512           /* k-rows per block in dots_kernel */

// ---------------- K1: f = l2norm(f @ W + b) for both s and t ----------------
// 256 threads: K split in two halves (serial fma chain 2048 -> 1024).
__global__ void gemm_norm_kernel(const float* __restrict__ f_s,
                                 const float* __restrict__ f_t,
                                 const float* __restrict__ W_s,
                                 const float* __restrict__ b_s,
                                 const float* __restrict__ W_t,
                                 const float* __restrict__ b_t,
                                 float* __restrict__ out_fs,
                                 float* __restrict__ out_ft)
{
    const int row = blockIdx.x;
    const int z   = blockIdx.y;
    const float* f    = z == 0 ? f_s : f_t;
    const float* W    = z == 0 ? W_s : W_t;
    const float* bias = z == 0 ? b_s : b_t;
    float* out        = z == 0 ? out_fs : out_ft;

    __shared__ __align__(16) float frow[SDIM];
    const int t  = threadIdx.x;        // 0..255
    const int d  = t & 127;
    const int kh = t >> 7;             // 0/1
    for (int k = t; k < SDIM; k += 256) frow[k] = f[row * SDIM + k];
    __syncthreads();

    float acc = 0.0f;
    const int k0 = kh * (SDIM / 2);
    for (int k = k0; k < k0 + SDIM / 2; ++k)
        acc = fmaf(frow[k], W[k * FEAT + d], acc);

    __shared__ float part[2][128];
    part[kh][d] = acc;
    __syncthreads();

    const float a = part[0][d] + part[1][d] + bias[d];

    __shared__ float red[256];
    red[t] = (t < 128) ? a * a : 0.0f;
    __syncthreads();
    for (int s = 128; s > 0; s >>= 1) {
        if (t < s) red[t] += red[t + s];
        __syncthreads();
    }
    if (t < 128) out[row * FEAT + t] = a * (1.0f / sqrtf(red[0]));
}

// ---- K2: out[z][b][k] = exp(dot(mem[ci], f[b]) / T), plus total sum S[z] ----
// Cooperative: 32 lanes per row (coalesced 512B row reads), 2 rows per
// wave-instruction. Each lane holds a fixed f-fragment in registers.
__global__ void dots_kernel(const float* __restrict__ fsn,
                            const float* __restrict__ ftn,
                            const int*   __restrict__ contrast_idx,
                            const float* __restrict__ mem_s,
                            const float* __restrict__ mem_t,
                            float* __restrict__ out_raw,   // [2][B*PK]
                            float* __restrict__ Ssum)      // [2]
{
    const int z    = blockIdx.z;
    const int b    = blockIdx.y;
    const int lane = threadIdx.x & 63;
    const int wave = threadIdx.x >> 6;     // 0..3
    const int half = lane >> 5;            // 0/1
    const int l32  = lane & 31;

    const int kbase = blockIdx.x * DCHUNK + wave * 128;
    if (kbase >= PK) return;               // whole wave out of range

    const float* f   = (z == 0 ? fsn : ftn) + b * FEAT;
    const float* mem = (z == 0 ? mem_t : mem_s);   // NOTE the cross pairing
    const float* memlane = mem + l32 * 4;

    // fixed per-lane f fragment
    const float4 ff = *(const float4*)(f + l32 * 4);

    __shared__ float xpose[4][64];
    float lsum = 0.0f;
    const size_t zoff = (size_t)z * (B * PK) + (size_t)b * PK;
    const float inv_t = 1.0f / 0.07f;

    for (int outer = 0; outer < 2; ++outer) {
        const int rowbase = kbase + outer * 64;
        const int klane = rowbase + lane;
        const int civ = contrast_idx[(size_t)b * PK + (klane < PK ? klane : PK - 1)];

        #pragma unroll 8
        for (int j = 0; j < 32; ++j) {
            const int r = 2 * j + half;
            const int ci = __shfl(civ, r);
            const float4 m = *(const float4*)(memlane + (size_t)ci * FEAT);
            float dot = m.x * ff.x;
            dot = fmaf(m.y, ff.y, dot);
            dot = fmaf(m.z, ff.z, dot);
            dot = fmaf(m.w, ff.w, dot);
            // reduce across the 32-lane group
            dot += __shfl_xor(dot, 16);
            dot += __shfl_xor(dot, 8);
            dot += __shfl_xor(dot, 4);
            dot += __shfl_xor(dot, 2);
            dot += __shfl_xor(dot, 1);
            const int krow = rowbase + r;
            const float val = (krow < PK) ? expf(dot * inv_t) : 0.0f;
            if (l32 == 0) xpose[wave][r] = val;
        }
        // coalesced store of the 64 values (same wave wrote them; compiler
        // inserts the lgkmcnt wait for the ds dependency)
        const float v = xpose[wave][lane];
        if (klane < PK) {
            out_raw[zoff + klane] = v;
            lsum += v;
        }
    }

    // wave reduction of lsum, one atomic per wave
    lsum += __shfl_xor(lsum, 32);
    lsum += __shfl_xor(lsum, 16);
    lsum += __shfl_xor(lsum, 8);
    lsum += __shfl_xor(lsum, 4);
    lsum += __shfl_xor(lsum, 2);
    lsum += __shfl_xor(lsum, 1);
    if (lane == 0) atomicAdd(&Ssum[z], lsum);
}

// ---- K3: accumulate acc[z] = sum logD1 + P * sum logD0 (weighted) ----
__global__ void ccd_loss_kernel(const float* __restrict__ out_raw,
                                const float* __restrict__ Ssum,
                                float* __restrict__ acc)   // [2]
{
    const int z = blockIdx.y;
    const float S = Ssum[z];
    // normalized v = out * c ; c = B*PK / (S * NDATA)
    const float c = ((float)(B * PK)) / (S * (float)NDATA);

    const int total = B * PK;
    float contrib = 0.0f;
    for (int i = blockIdx.x * blockDim.x + threadIdx.x; i < total;
         i += gridDim.x * blockDim.x) {
        const float v = out_raw[(size_t)z * total + i] * c;
        const int k = i % PK;
        if (k < P) {
            contrib += logf(v / (v + M_PN + EPSC));
        } else {
            contrib += (float)P * logf(M_PN / (v + M_PN + EPSC));
        }
    }
    __shared__ float red[256];
    red[threadIdx.x] = contrib;
    __syncthreads();
    for (int s = 128; s > 0; s >>= 1) {
        if (threadIdx.x < s) red[threadIdx.x] += red[threadIdx.x + s];
        __syncthreads();
    }
    if (threadIdx.x == 0) atomicAdd(&acc[z], red[0]);
}

// ---- K4: upd[z][b] = l2norm(mem[idx[b]]*0.5 + f[b]*0.5) ----
__global__ void upd_kernel(const float* __restrict__ fsn,
                           const float* __restrict__ ftn,
                           const int*   __restrict__ idx,
                           const float* __restrict__ mem_s,
                           const float* __restrict__ mem_t,
                           float* __restrict__ upd)   // [2][B*FEAT]
{
    const int z = blockIdx.y;
    const int b = blockIdx.x;
    const int d = threadIdx.x;  // 128
    const float* mem = z == 0 ? mem_s : mem_t;
    const float* f   = z == 0 ? fsn : ftn;
    const int i = idx[b];
    const float v = mem[(size_t)i * FEAT + d] * 0.5f + f[b * FEAT + d] * 0.5f;
    __shared__ float red[128];
    red[d] = v * v;
    __syncthreads();
    for (int s = 64; s > 0; s >>= 1) {
        if (d < s) red[d] += red[d + s];
        __syncthreads();
    }
    upd[(size_t)z * (B * FEAT) + b * FEAT + d] = v * (1.0f / sqrtf(red[0]));
}

// ---- K4b: remap[e] = last b with idx[b]==class_index[e], else -1 ----
__global__ void remap_kernel(const int* __restrict__ class_index,
                             const int* __restrict__ idx,
                             int* __restrict__ remap)
{
    const int e = blockIdx.x * 256 + threadIdx.x;
    if (e >= NCLS * PER) return;
    const int ci = class_index[e];
    int rb = -1;
    for (int b = B - 1; b >= 0; --b) {
        if (idx[b] == ci) { rb = b; break; }   // last occurrence wins
    }
    remap[e] = rb;
}

// ---- K5a: partial[z][c][d] += sum_{j in chunk} relu(new_mem[ci[c,j]][d]) ----
__global__ void anchors_partial_kernel(const int* __restrict__ class_index,
                                       const int* __restrict__ remap,
                                       const float* __restrict__ mem_s,
                                       const float* __restrict__ mem_t,
                                       const float* __restrict__ upd,
                                       float* __restrict__ partial) // [2][NCLS*FEAT]
{
    const int z     = blockIdx.z;
    const int c     = blockIdx.y;
    const int chunk = blockIdx.x;
    const int d     = threadIdx.x;  // 128
    const float* mem = z == 0 ? mem_s : mem_t;
    const float* u   = upd + (size_t)z * (B * FEAT);
    float acc = 0.0f;
    #pragma unroll 4
    for (int j = chunk * CS; j < chunk * CS + CS; ++j) {
        const int e = c * PER + j;
        const int ci = class_index[e];
        const int rb = remap[e];
        const float* row = (rb >= 0) ? (u + rb * FEAT) : (mem + (size_t)ci * FEAT);
        const float v = row[d];
        acc += v > 0.0f ? v : 0.0f;
    }
    atomicAdd(&partial[(size_t)z * (NCLS * FEAT) + c * FEAT + d], acc);
}

// ---- K5b: anchors[z][c] = l2norm(partial / PER) ----
__global__ void anchors_finish_kernel(const float* __restrict__ partial,
                                      float* __restrict__ anchors)  // [2][NCLS*FEAT]
{
    const int z = blockIdx.y;
    const int c = blockIdx.x;
    const int d = threadIdx.x;  // 128
    const float meanv = partial[(size_t)z * (NCLS * FEAT) + c * FEAT + d]
                        * (1.0f / (float)PER);
    __shared__ float red[128];
    red[d] = meanv * meanv;
    __syncthreads();
    for (int s = 64; s > 0; s >>= 1) {
        if (d < s) red[d] += red[d + s];
        __syncthreads();
    }
    anchors[(size_t)z * (NCLS * FEAT) + c * FEAT + d] = meanv * (1.0f / sqrtf(red[0]));
}

// ---- K6: relation loss (softmax KL) + final CCD assembly ----
__global__ void final_kernel(const float* __restrict__ fsn,
                             const float* __restrict__ ftn,
                             const float* __restrict__ anchors,
                             const float* __restrict__ acc,
                             float* __restrict__ d_out)
{
    __shared__ float sa[NCLS * FEAT];
    __shared__ float ta[NCLS * FEAT];
    const int tid = threadIdx.x;  // 64 threads
    for (int i = tid; i < NCLS * FEAT; i += 64) {
        sa[i] = anchors[i];
        ta[i] = anchors[NCLS * FEAT + i];
    }
    __syncthreads();

    const int b = tid;
    float srel[NCLS], trel[NCLS];
    for (int j = 0; j < NCLS; ++j) { srel[j] = 0.0f; trel[j] = 0.0f; }
    for (int d = 0; d < FEAT; ++d) {
        const float fs = fsn[b * FEAT + d];
        const float ft = ftn[b * FEAT + d];
        #pragma unroll
        for (int j = 0; j < NCLS; ++j) {
            srel[j] = fmaf(fs, sa[j * FEAT + d], srel[j]);
            trel[j] = fmaf(ft, ta[j * FEAT + d], trel[j]);
        }
    }
    const float inv_t = 1.0f / 0.07f;
    float smax = -1e30f, tmax = -1e30f;
    for (int j = 0; j < NCLS; ++j) {
        srel[j] *= inv_t; trel[j] *= inv_t;
        smax = fmaxf(smax, srel[j]);
        tmax = fmaxf(tmax, trel[j]);
    }
    float ssum = 0.0f, tsum = 0.0f;
    float texp[NCLS];
    for (int j = 0; j < NCLS; ++j) {
        ssum += expf(srel[j] - smax);
        texp[j] = expf(trel[j] - tmax);
        tsum += texp[j];
    }
    const float lse_s = logf(ssum);
    float contrib = 0.0f;
    for (int j = 0; j < NCLS; ++j) {
        const float tgt = texp[j] / tsum;
        const float log_in = srel[j] - smax - lse_s;   // log_softmax
        contrib += tgt * (logf(tgt + 1e-30f) - log_in);
    }
    for (int off = 32; off > 0; off >>= 1) contrib += __shfl_down(contrib, off);
    if (tid == 0) {
        d_out[1] = contrib / (float)B;
        d_out[0] = -(acc[0] + acc[1]) / (float)(B * P);
    }
}

extern "C" void kernel_launch(void* const* d_in, const int* in_sizes, int n_in,
                              void* d_out_v, int out_size, void* d_ws, size_t ws_size,
                              hipStream_t stream)
{
    const float* f_s = (const float*)d_in[0];
    const float* f_t = (const float*)d_in[1];
    const int*   idx = (const int*)d_in[2];
    /* d_in[3] batch_label: unused by reference */
    const int*   class_index = (const int*)d_in[4];
    /* d_in[5] num_pos == 4 (hardcoded) */
    const int*   contrast_idx = (const int*)d_in[6];
    const float* W_s = (const float*)d_in[7];
    const float* b_s = (const float*)d_in[8];
    const float* W_t = (const float*)d_in[9];
    const float* b_t = (const float*)d_in[10];
    const float* mem_s = (const float*)d_in[11];
    const float* mem_t = (const float*)d_in[12];

    float* out    = (float*)d_out_v;
    float* out_fs = out + 2;               // f_s output (64*128)
    float* out_ft = out + 2 + B * FEAT;    // f_t output

    // workspace layout (floats)
    float* ws      = (float*)d_ws;
    float* out_raw = ws;                          // 2 * B*PK   = 1,049,088
    float* Ssum    = out_raw + 2 * (B * PK);      // 2
    float* acc     = Ssum + 2;                    // 2
    float* upd     = acc + 2;                     // 2 * B*FEAT = 16,384
    float* anchors = upd + 2 * (B * FEAT);        // 2 * NCLS*FEAT = 1,792
    float* partial = anchors + 2 * (NCLS * FEAT); // 2 * NCLS*FEAT = 1,792
    int*   remap   = (int*)(partial + 2 * (NCLS * FEAT));  // 7,000 ints

    // zero Ssum[2] + acc[2] + partial[1792]
    hipMemsetAsync(Ssum, 0, 4 * sizeof(float), stream);
    hipMemsetAsync(partial, 0, 2 * NCLS * FEAT * sizeof(float), stream);

    dim3 g1(B, 2);
    gemm_norm_kernel<<<g1, 256, 0, stream>>>(f_s, f_t, W_s, b_s, W_t, b_t,
                                             out_fs, out_ft);
    dim3 g2((PK + DCHUNK - 1) / DCHUNK, B, 2);   // 17 x 64 x 2
    dots_kernel<<<g2, 256, 0, stream>>>(out_fs, out_ft, contrast_idx,
                                        mem_s, mem_t, out_raw, Ssum);
    dim3 g3(256, 2);
    ccd_loss_kernel<<<g3, 256, 0, stream>>>(out_raw, Ssum, acc);
    dim3 g4(B, 2);
    upd_kernel<<<g4, 128, 0, stream>>>(out_fs, out_ft, idx, mem_s, mem_t, upd);
    remap_kernel<<<(NCLS * PER + 255) / 256, 256, 0, stream>>>(class_index, idx, remap);
    dim3 g5a(JCHUNKS, NCLS, 2);
    anchors_partial_kernel<<<g5a, 128, 0, stream>>>(class_index, remap,
                                                    mem_s, mem_t, upd, partial);
    dim3 g5b(NCLS, 2);
    anchors_finish_kernel<<<g5b, 128, 0, stream>>>(partial, anchors);
    final_kernel<<<1, 64, 0, stream>>>(out_fs, out_ft, anchors, acc, out);
}

// Round 4
// 165.329 us; speedup vs baseline: 1.6350x; 1.6350x over previous
//
#include <hip/hip_runtime.h>
#include <math.h>

#define B 64
#define SDIM 2048
#define FEAT 128
#define P 4
#define PK 8196
#define NCLS 7
#define PER 1000
#define NDATA 100000
#define EPSC 1e-7f
#define M_PN 0.08192f   /* (PK-P)/NDATA = 8192/100000 */
#define JCHUNKS 50
#define CS (PER / JCHUNKS)   /* 20 rows per block */
#define TILE 32              /* rows per LDS tile in dots_kernel */
#define TCHUNK 512           /* k-rows per block in dots_kernel */
#define NTILES (TCHUNK / TILE)

// ---------------- K1: f = l2norm(f @ W + b) for both s and t ----------------
__global__ void gemm_norm_kernel(const float* __restrict__ f_s,
                                 const float* __restrict__ f_t,
                                 const float* __restrict__ W_s,
                                 const float* __restrict__ b_s,
                                 const float* __restrict__ W_t,
                                 const float* __restrict__ b_t,
                                 float* __restrict__ out_fs,
                                 float* __restrict__ out_ft)
{
    const int row = blockIdx.x;
    const int z   = blockIdx.y;
    const float* f    = z == 0 ? f_s : f_t;
    const float* W    = z == 0 ? W_s : W_t;
    const float* bias = z == 0 ? b_s : b_t;
    float* out        = z == 0 ? out_fs : out_ft;

    __shared__ __align__(16) float frow[SDIM];
    const int t  = threadIdx.x;        // 0..255
    const int d  = t & 127;
    const int kh = t >> 7;             // 0/1
    for (int k = t; k < SDIM; k += 256) frow[k] = f[row * SDIM + k];
    __syncthreads();

    float acc = 0.0f;
    const int k0 = kh * (SDIM / 2);
    for (int k = k0; k < k0 + SDIM / 2; ++k)
        acc = fmaf(frow[k], W[k * FEAT + d], acc);

    __shared__ float part[2][128];
    part[kh][d] = acc;
    __syncthreads();

    const float a = part[0][d] + part[1][d] + bias[d];

    __shared__ float red[256];
    red[t] = (t < 128) ? a * a : 0.0f;
    __syncthreads();
    for (int s = 128; s > 0; s >>= 1) {
        if (t < s) red[t] += red[t + s];
        __syncthreads();
    }
    if (t < 128) out[row * FEAT + t] = a * (1.0f / sqrtf(red[0]));
}

// ---- K2: out[z][b][k] = exp(dot(mem[ci], f[b]) / T), plus total sum S[z] ----
// 1 wave/block. Coalesced gather (32 lanes per 512B row) -> XOR-swizzled LDS
// tile -> per-lane half-row dot from LDS (zero shuffles in inner loops, one
// shfl_xor per row at the end).
__global__ __launch_bounds__(64)
void dots_kernel(const float* __restrict__ fsn,
                 const float* __restrict__ ftn,
                 const int*   __restrict__ contrast_idx,
                 const float* __restrict__ mem_s,
                 const float* __restrict__ mem_t,
                 float* __restrict__ out_raw,   // [2][B*PK]
                 float* __restrict__ Ssum)      // [2]
{
    const int z = blockIdx.z;
    const int b = blockIdx.y;
    const int l = threadIdx.x;         // 0..63
    const int kchunk = blockIdx.x * TCHUNK;

    const float* f   = (z == 0 ? fsn : ftn) + b * FEAT;
    const float* mem = (z == 0 ? mem_t : mem_s);   // NOTE the cross pairing

    __shared__ __align__(16) float4 rows[TILE * 32];   // 16 KB, swizzled
    __shared__ __align__(16) float  fl[FEAT];          // 512 B
    __shared__ int cis[TCHUNK];                        // 2 KB

    // stage f (broadcast source for compute phase)
    fl[l]      = f[l];
    fl[l + 64] = f[l + 64];
    // stage ci chunk, guarded at PK
    for (int i = 0; i < TCHUNK; i += 64) {
        const int k = kchunk + i + l;
        cis[i + l] = contrast_idx[(size_t)b * PK + (k < PK ? k : PK - 1)];
    }
    __syncthreads();

    const int h   = l >> 5;            // 0/1: which half-row this lane owns
    const int g32 = l & 31;            // float4 slot within a row (stage)
    const int r_c = l & 31;            // row this lane computes
    const int xk  = r_c & 7;           // compute-phase swizzle key
    const float inv_t = 1.0f / 0.07f;
    const size_t obase = (size_t)z * (B * PK) + (size_t)b * PK;
    const float4* fp4 = (const float4*)fl;

    float lsum = 0.0f;

    for (int t = 0; t < NTILES; ++t) {
        const int rowbase = kchunk + t * TILE;
        if (rowbase >= PK) break;      // uniform across the wave

        // ---- stage TILE rows, coalesced: 2 rows per pass ----
        #pragma unroll
        for (int p = 0; p < TILE / 2; ++p) {
            const int r  = 2 * p + h;
            const int ci = cis[t * TILE + r];   // LDS broadcast (2 addrs/wave)
            const float4 v =
                *(const float4*)(mem + (size_t)ci * FEAT + g32 * 4);
            rows[r * 32 + (g32 ^ (r & 7))] = v;
        }
        __syncthreads();

        // ---- compute: lane l does half (h) of row r_c ----
        float dot = 0.0f;
        #pragma unroll
        for (int i = 0; i < 16; ++i) {
            const int g = h * 16 + i;
            const float4 m  = rows[r_c * 32 + (g ^ xk)];
            const float4 ff = fp4[g];
            dot = fmaf(m.x, ff.x, dot);
            dot = fmaf(m.y, ff.y, dot);
            dot = fmaf(m.z, ff.z, dot);
            dot = fmaf(m.w, ff.w, dot);
        }
        dot += __shfl_xor(dot, 32);    // combine the two halves

        const int krow = rowbase + r_c;
        if (h == 0 && krow < PK) {
            const float val = expf(dot * inv_t);
            out_raw[obase + krow] = val;
            lsum += val;
        }
        __syncthreads();               // protect rows[] before next stage
    }

    // reduce lsum over lanes 0..31 (h==1 lanes hold 0)
    lsum += __shfl_xor(lsum, 16);
    lsum += __shfl_xor(lsum, 8);
    lsum += __shfl_xor(lsum, 4);
    lsum += __shfl_xor(lsum, 2);
    lsum += __shfl_xor(lsum, 1);
    if (l == 0) atomicAdd(&Ssum[z], lsum);
}

// ---- K3: accumulate acc[z] = sum logD1 + P * sum logD0 (weighted) ----
__global__ void ccd_loss_kernel(const float* __restrict__ out_raw,
                                const float* __restrict__ Ssum,
                                float* __restrict__ acc)   // [2]
{
    const int z = blockIdx.y;
    const float S = Ssum[z];
    // normalized v = out * c ; c = B*PK / (S * NDATA)
    const float c = ((float)(B * PK)) / (S * (float)NDATA);

    const int total = B * PK;
    float contrib = 0.0f;
    for (int i = blockIdx.x * blockDim.x + threadIdx.x; i < total;
         i += gridDim.x * blockDim.x) {
        const float v = out_raw[(size_t)z * total + i] * c;
        const int k = i % PK;
        if (k < P) {
            contrib += logf(v / (v + M_PN + EPSC));
        } else {
            contrib += (float)P * logf(M_PN / (v + M_PN + EPSC));
        }
    }
    __shared__ float red[256];
    red[threadIdx.x] = contrib;
    __syncthreads();
    for (int s = 128; s > 0; s >>= 1) {
        if (threadIdx.x < s) red[threadIdx.x] += red[threadIdx.x + s];
        __syncthreads();
    }
    if (threadIdx.x == 0) atomicAdd(&acc[z], red[0]);
}

// ---- K4: upd[z][b] = l2norm(mem[idx[b]]*0.5 + f[b]*0.5) ----
__global__ void upd_kernel(const float* __restrict__ fsn,
                           const float* __restrict__ ftn,
                           const int*   __restrict__ idx,
                           const float* __restrict__ mem_s,
                           const float* __restrict__ mem_t,
                           float* __restrict__ upd)   // [2][B*FEAT]
{
    const int z = blockIdx.y;
    const int b = blockIdx.x;
    const int d = threadIdx.x;  // 128
    const float* mem = z == 0 ? mem_s : mem_t;
    const float* f   = z == 0 ? fsn : ftn;
    const int i = idx[b];
    const float v = mem[(size_t)i * FEAT + d] * 0.5f + f[b * FEAT + d] * 0.5f;
    __shared__ float red[128];
    red[d] = v * v;
    __syncthreads();
    for (int s = 64; s > 0; s >>= 1) {
        if (d < s) red[d] += red[d + s];
        __syncthreads();
    }
    upd[(size_t)z * (B * FEAT) + b * FEAT + d] = v * (1.0f / sqrtf(red[0]));
}

// ---- K4b: remap[e] = last b with idx[b]==class_index[e], else -1 ----
__global__ void remap_kernel(const int* __restrict__ class_index,
                             const int* __restrict__ idx,
                             int* __restrict__ remap)
{
    const int e = blockIdx.x * 256 + threadIdx.x;
    if (e >= NCLS * PER) return;
    const int ci = class_index[e];
    int rb = -1;
    for (int b = B - 1; b >= 0; --b) {
        if (idx[b] == ci) { rb = b; break; }   // last occurrence wins
    }
    remap[e] = rb;
}

// ---- K5a: partial[z][c][d] += sum_{j in chunk} relu(new_mem[ci[c,j]][d]) ----
__global__ void anchors_partial_kernel(const int* __restrict__ class_index,
                                       const int* __restrict__ remap,
                                       const float* __restrict__ mem_s,
                                       const float* __restrict__ mem_t,
                                       const float* __restrict__ upd,
                                       float* __restrict__ partial) // [2][NCLS*FEAT]
{
    const int z     = blockIdx.z;
    const int c     = blockIdx.y;
    const int chunk = blockIdx.x;
    const int d     = threadIdx.x;  // 128
    const float* mem = z == 0 ? mem_s : mem_t;
    const float* u   = upd + (size_t)z * (B * FEAT);
    float acc = 0.0f;
    #pragma unroll 4
    for (int j = chunk * CS; j < chunk * CS + CS; ++j) {
        const int e = c * PER + j;
        const int ci = class_index[e];
        const int rb = remap[e];
        const float* row = (rb >= 0) ? (u + rb * FEAT) : (mem + (size_t)ci * FEAT);
        const float v = row[d];
        acc += v > 0.0f ? v : 0.0f;
    }
    atomicAdd(&partial[(size_t)z * (NCLS * FEAT) + c * FEAT + d], acc);
}

// ---- K5b: anchors[z][c] = l2norm(partial / PER) ----
__global__ void anchors_finish_kernel(const float* __restrict__ partial,
                                      float* __restrict__ anchors)  // [2][NCLS*FEAT]
{
    const int z = blockIdx.y;
    const int c = blockIdx.x;
    const int d = threadIdx.x;  // 128
    const float meanv = partial[(size_t)z * (NCLS * FEAT) + c * FEAT + d]
                        * (1.0f / (float)PER);
    __shared__ float red[128];
    red[d] = meanv * meanv;
    __syncthreads();
    for (int s = 64; s > 0; s >>= 1) {
        if (d < s) red[d] += red[d + s];
        __syncthreads();
    }
    anchors[(size_t)z * (NCLS * FEAT) + c * FEAT + d] = meanv * (1.0f / sqrtf(red[0]));
}

// ---- K6: relation loss (softmax KL) + final CCD assembly ----
__global__ void final_kernel(const float* __restrict__ fsn,
                             const float* __restrict__ ftn,
                             const float* __restrict__ anchors,
                             const float* __restrict__ acc,
                             float* __restrict__ d_out)
{
    __shared__ float sa[NCLS * FEAT];
    __shared__ float ta[NCLS * FEAT];
    const int tid = threadIdx.x;  // 64 threads
    for (int i = tid; i < NCLS * FEAT; i += 64) {
        sa[i] = anchors[i];
        ta[i] = anchors[NCLS * FEAT + i];
    }
    __syncthreads();

    const int b = tid;
    float srel[NCLS], trel[NCLS];
    for (int j = 0; j < NCLS; ++j) { srel[j] = 0.0f; trel[j] = 0.0f; }
    for (int d = 0; d < FEAT; ++d) {
        const float fs = fsn[b * FEAT + d];
        const float ft = ftn[b * FEAT + d];
        #pragma unroll
        for (int j = 0; j < NCLS; ++j) {
            srel[j] = fmaf(fs, sa[j * FEAT + d], srel[j]);
            trel[j] = fmaf(ft, ta[j * FEAT + d], trel[j]);
        }
    }
    const float inv_t = 1.0f / 0.07f;
    float smax = -1e30f, tmax = -1e30f;
    for (int j = 0; j < NCLS; ++j) {
        srel[j] *= inv_t; trel[j] *= inv_t;
        smax = fmaxf(smax, srel[j]);
        tmax = fmaxf(tmax, trel[j]);
    }
    float ssum = 0.0f, tsum = 0.0f;
    float texp[NCLS];
    for (int j = 0; j < NCLS; ++j) {
        ssum += expf(srel[j] - smax);
        texp[j] = expf(trel[j] - tmax);
        tsum += texp[j];
    }
    const float lse_s = logf(ssum);
    float contrib = 0.0f;
    for (int j = 0; j < NCLS; ++j) {
        const float tgt = texp[j] / tsum;
        const float log_in = srel[j] - smax - lse_s;   // log_softmax
        contrib += tgt * (logf(tgt + 1e-30f) - log_in);
    }
    for (int off = 32; off > 0; off >>= 1) contrib += __shfl_down(contrib, off);
    if (tid == 0) {
        d_out[1] = contrib / (float)B;
        d_out[0] = -(acc[0] + acc[1]) / (float)(B * P);
    }
}

extern "C" void kernel_launch(void* const* d_in, const int* in_sizes, int n_in,
                              void* d_out_v, int out_size, void* d_ws, size_t ws_size,
                              hipStream_t stream)
{
    const float* f_s = (const float*)d_in[0];
    const float* f_t = (const float*)d_in[1];
    const int*   idx = (const int*)d_in[2];
    /* d_in[3] batch_label: unused by reference */
    const int*   class_index = (const int*)d_in[4];
    /* d_in[5] num_pos == 4 (hardcoded) */
    const int*   contrast_idx = (const int*)d_in[6];
    const float* W_s = (const float*)d_in[7];
    const float* b_s = (const float*)d_in[8];
    const float* W_t = (const float*)d_in[9];
    const float* b_t = (const float*)d_in[10];
    const float* mem_s = (const float*)d_in[11];
    const float* mem_t = (const float*)d_in[12];

    float* out    = (float*)d_out_v;
    float* out_fs = out + 2;               // f_s output (64*128)
    float* out_ft = out + 2 + B * FEAT;    // f_t output

    // workspace layout (floats)
    float* ws      = (float*)d_ws;
    float* out_raw = ws;                          // 2 * B*PK   = 1,049,088
    float* Ssum    = out_raw + 2 * (B * PK);      // 2
    float* acc     = Ssum + 2;                    // 2
    float* upd     = acc + 2;                     // 2 * B*FEAT = 16,384
    float* anchors = upd + 2 * (B * FEAT);        // 2 * NCLS*FEAT = 1,792
    float* partial = anchors + 2 * (NCLS * FEAT); // 2 * NCLS*FEAT = 1,792
    int*   remap   = (int*)(partial + 2 * (NCLS * FEAT));  // 7,000 ints

    // zero Ssum[2] + acc[2] + partial[1792]
    hipMemsetAsync(Ssum, 0, 4 * sizeof(float), stream);
    hipMemsetAsync(partial, 0, 2 * NCLS * FEAT * sizeof(float), stream);

    dim3 g1(B, 2);
    gemm_norm_kernel<<<g1, 256, 0, stream>>>(f_s, f_t, W_s, b_s, W_t, b_t,
                                             out_fs, out_ft);
    dim3 g2((PK + TCHUNK - 1) / TCHUNK, B, 2);   // 17 x 64 x 2
    dots_kernel<<<g2, 64, 0, stream>>>(out_fs, out_ft, contrast_idx,
                                       mem_s, mem_t, out_raw, Ssum);
    dim3 g3(256, 2);
    ccd_loss_kernel<<<g3, 256, 0, stream>>>(out_raw, Ssum, acc);
    dim3 g4(B, 2);
    upd_kernel<<<g4, 128, 0, stream>>>(out_fs, out_ft, idx, mem_s, mem_t, upd);
    remap_kernel<<<(NCLS * PER + 255) / 256, 256, 0, stream>>>(class_index, idx, remap);
    dim3 g5a(JCHUNKS, NCLS, 2);
    anchors_partial_kernel<<<g5a, 128, 0, stream>>>(class_index, remap,
                                                    mem_s, mem_t, upd, partial);
    dim3 g5b(NCLS, 2);
    anchors_finish_kernel<<<g5b, 128, 0, stream>>>(partial, anchors);
    final_kernel<<<1, 64, 0, stream>>>(out_fs, out_ft, anchors, acc, out);
}